// Round 1
// baseline (5731.616 us; speedup 1.0000x reference)
//
#include <hip/hip_runtime.h>
#include <math.h>

#define NN 200000
#define EE 300000
#define BB 300
#define KK 10
#define DD 172
#define MSGD 100
#define QDIM 344   // 2*D
#define KDIM 516   // 3*D
#define RAWD 689   // 4*D+1
#define RAWH 344   // RAWD/2

// ---------------- map fill ----------------
__global__ __launch_bounds__(256) void fill_map(int* map) {
  int i = blockIdx.x * 256 + threadIdx.x;
  if (i < NN) map[i] = -1;
}

__global__ __launch_bounds__(64) void set_map(int* map, const int* src, const int* dst) {
  int i = blockIdx.x * 64 + threadIdx.x;
  if (i < BB) { map[src[i]] = i; map[dst[i]] = BB + i; }
}

// ---------------- message + GRU memory update ----------------
// block r in [0, 2B): r<B -> update src[r] with msg(src,dst); else dst[r-B] with msg(dst,src)
__global__ __launch_bounds__(256) void msg_gru(
    const float* memory, const float* edge_features, const float* last_update,
    const float* time_w, const float* time_b,
    const float* num_w1, const float* num_b1, const float* num_w2, const float* num_b2,
    const float* msg_w1, const float* msg_b1, const float* msg_w2, const float* msg_b2,
    const float* gru_wih, const float* gru_whh, const float* gru_bih, const float* gru_bhh,
    const float* edge_times, const float* num_conn,
    const int* src, const int* dst, const int* edge_idxs,
    float* upd) {
  __shared__ float s_raw[RAWD];
  __shared__ float s_h1[RAWH];
  __shared__ float s_msg[MSGD];
  __shared__ float s_gi[3 * DD];
  __shared__ float s_gh[3 * DD];

  const int r = blockIdx.x;
  const int e = (r < BB) ? r : r - BB;
  const int a = (r < BB) ? src[e] : dst[e];
  const int b = (r < BB) ? dst[e] : src[e];
  const int t = threadIdx.x;
  const int ei = edge_idxs[e];
  const float dt = edge_times[e] - last_update[a];

  for (int d = t; d < DD; d += 256) {
    s_raw[d]          = memory[(size_t)a * DD + d];
    s_raw[DD + d]     = memory[(size_t)b * DD + d];
    s_raw[2 * DD + d] = edge_features[(size_t)ei * DD + d];
    s_raw[3 * DD + d] = cosf(dt * time_w[d] + time_b[d]);
  }
  if (t == 0) {
    float ne = fmaxf(num_conn[e] * num_w1[0] + num_b1[0], 0.f) * num_w2[0] + num_b2[0];
    s_raw[4 * DD] = ne;
  }
  __syncthreads();

  for (int j = t; j < RAWH; j += 256) {
    float acc = msg_b1[j];
    for (int i = 0; i < RAWD; i++) acc += s_raw[i] * msg_w1[(size_t)i * RAWH + j];
    s_h1[j] = fmaxf(acc, 0.f);
  }
  __syncthreads();
  for (int j = t; j < MSGD; j += 256) {
    float acc = msg_b2[j];
    for (int i = 0; i < RAWH; i++) acc += s_h1[i] * msg_w2[(size_t)i * MSGD + j];
    s_msg[j] = acc;
  }
  __syncthreads();
  for (int j = t; j < 3 * DD; j += 256) {
    float gi = gru_bih[j];
    for (int k = 0; k < MSGD; k++) gi += s_msg[k] * gru_wih[(size_t)j * MSGD + k];
    s_gi[j] = gi;
    float gh = gru_bhh[j];
    for (int k = 0; k < DD; k++) gh += s_raw[k] * gru_whh[(size_t)j * DD + k];
    s_gh[j] = gh;
  }
  __syncthreads();
  for (int d = t; d < DD; d += 256) {
    float rg = 1.f / (1.f + expf(-(s_gi[d] + s_gh[d])));
    float z  = 1.f / (1.f + expf(-(s_gi[DD + d] + s_gh[DD + d])));
    float nn = tanhf(s_gi[2 * DD + d] + rg * s_gh[2 * DD + d]);
    upd[(size_t)r * DD + d] = (1.f - z) * nn + z * s_raw[d];
  }
}

// ---------------- fused attention ----------------
struct AttnArgs {
  const float* node_features;
  const float* memory;
  const float* upd;
  const int* map;
  const float* edge_features;
  const float* time_w;
  const float* time_b;
  const float* wq; const float* wk; const float* wv;
  const float* bq; const float* bk; const float* bv;
  const float* wo; const float* bo;
  const float* m1w; const float* m1b; const float* m2w; const float* m2b;
  const float* edge_times;
  const int* src; const int* dst; const int* neg;
  const int* center_ids;     // mode 1: n1_nb flat
  const int* nb; const int* eidx; const float* et;
  const float* src_conv_in;  // mode 2
  const float* neigh_in;     // mode 2
  float* out;
};

// MODE 0: layer-1 emb of targets (src/dst/neg), feat() inputs, n1_* tables
// MODE 1: layer-1 emb of 1-hop neighbors, feat() inputs, n2_* tables
// MODE 2: layer-2 aggregation: src_conv_in + neigh_in (no feat), n1_* tables
template <int MODE>
__global__ __launch_bounds__(256) void attn_kernel(AttnArgs A) {
  __shared__ float s_kin[KK][KDIM];
  __shared__ float s_src[DD];
  __shared__ float s_qin[QDIM];
  __shared__ float s_q[QDIM];
  __shared__ float s_k[KK][QDIM];
  __shared__ float s_v[KK][QDIM];
  __shared__ float s_sc[2][KK];
  __shared__ float s_att[2][KK];
  __shared__ float s_o[QDIM];
  __shared__ float s_o2[QDIM];
  __shared__ float s_m1[DD];
  __shared__ int s_nb[KK];
  __shared__ int s_ei[KK];
  __shared__ float s_et[KK];
  __shared__ int s_allmask;

  const int i = blockIdx.x;
  const int t = threadIdx.x;
  const float ts = (MODE == 1) ? A.edge_times[(i / KK) % BB] : A.edge_times[i % BB];

  if (t < KK) {
    s_nb[t] = A.nb[i * KK + t];
    s_ei[t] = A.eidx[i * KK + t];
    s_et[t] = A.et[i * KK + t];
  }

  if (MODE == 2) {
    for (int d = t; d < DD; d += 256) {
      float v = A.src_conv_in[(size_t)i * DD + d];
      s_src[d] = v; s_qin[d] = v;
      s_qin[DD + d] = cosf(A.time_b[d]);   // time_enc(0)
    }
  } else {
    int node;
    if (MODE == 0) node = (i < BB) ? A.src[i] : (i < 2 * BB ? A.dst[i - BB] : A.neg[i - 2 * BB]);
    else           node = A.center_ids[i];
    const int m = A.map[node];
    const float* mrow = (m >= 0) ? (A.upd + (size_t)m * DD) : (A.memory + (size_t)node * DD);
    for (int d = t; d < DD; d += 256) {
      float v = mrow[d] + A.node_features[(size_t)node * DD + d];
      s_src[d] = v; s_qin[d] = v;
      s_qin[DD + d] = cosf(A.time_b[d]);
    }
  }
  __syncthreads();

  if (t == 0) {
    int am = 1;
    for (int k = 0; k < KK; k++) if (s_nb[k] != 0) am = 0;
    s_allmask = am;
  }

  // build k_in = [neigh_emb | edge_feat | time_enc(ts - et)]
  for (int f = t; f < KK * KDIM; f += 256) {
    int k = f / KDIM, c = f - k * KDIM;
    float val;
    if (c < DD) {
      if (MODE == 2) {
        val = A.neigh_in[((size_t)i * KK + k) * DD + c];
      } else {
        int nbid = s_nb[k];
        int m = A.map[nbid];
        const float* mrow = (m >= 0) ? (A.upd + (size_t)m * DD) : (A.memory + (size_t)nbid * DD);
        val = mrow[c] + A.node_features[(size_t)nbid * DD + c];
      }
    } else if (c < 2 * DD) {
      val = A.edge_features[(size_t)s_ei[k] * DD + (c - DD)];
    } else {
      int d = c - 2 * DD;
      val = cosf((ts - s_et[k]) * A.time_w[d] + A.time_b[d]);
    }
    s_kin[k][c] = val;
  }
  __syncthreads();

  // q projection [344]
  for (int j = t; j < QDIM; j += 256) {
    float acc = A.bq[j];
    for (int x = 0; x < QDIM; x++) acc += s_qin[x] * A.wq[(size_t)x * QDIM + j];
    s_q[j] = acc;
  }
  // k,v projections: column-major, 10-row accumulator (weight reuse x10)
  for (int col = t; col < 2 * QDIM; col += 256) {
    int which = col / QDIM;
    int j = col - which * QDIM;
    const float* w = which ? A.wv : A.wk;
    float bias = which ? A.bv[j] : A.bk[j];
    float acc[KK];
#pragma unroll
    for (int r = 0; r < KK; r++) acc[r] = bias;
#pragma unroll 4
    for (int x = 0; x < KDIM; x++) {
      float wv_ = w[(size_t)x * QDIM + j];
#pragma unroll
      for (int r = 0; r < KK; r++) acc[r] += s_kin[r][x] * wv_;
    }
    float* outp = which ? &s_v[0][0] : &s_k[0][0];
#pragma unroll
    for (int r = 0; r < KK; r++) outp[r * QDIM + j] = acc[r];
  }
  __syncthreads();

  // scores (H=2 heads, dh=172)
  if (t < 2 * KK) {
    int h = t / KK, kk = t - (t / KK) * KK;
    float acc = 0.f;
    for (int d = 0; d < DD; d++) acc += s_q[h * DD + d] * s_k[kk][h * DD + d];
    acc /= sqrtf((float)DD);
    if (s_nb[kk] == 0) acc = -1e9f;
    s_sc[h][kk] = acc;
  }
  __syncthreads();
  if (t < 2) {
    float mx = -1e30f;
    for (int kk = 0; kk < KK; kk++) mx = fmaxf(mx, s_sc[t][kk]);
    float sum = 0.f, ex[KK];
    for (int kk = 0; kk < KK; kk++) { ex[kk] = expf(s_sc[t][kk] - mx); sum += ex[kk]; }
    float inv = 1.f / sum;
    for (int kk = 0; kk < KK; kk++) s_att[t][kk] = ex[kk] * inv;
  }
  __syncthreads();

  // attn-weighted V
  for (int j = t; j < QDIM; j += 256) {
    int h = j / DD;
    float acc = 0.f;
#pragma unroll
    for (int kk = 0; kk < KK; kk++) acc += s_att[h][kk] * s_v[kk][j];
    s_o[j] = acc;
  }
  __syncthreads();
  // output projection + invalid-neighborhood zeroing
  for (int j = t; j < QDIM; j += 256) {
    float acc = A.bo[j];
    for (int x = 0; x < QDIM; x++) acc += s_o[x] * A.wo[(size_t)x * QDIM + j];
    s_o2[j] = s_allmask ? 0.f : acc;
  }
  __syncthreads();
  // merge layer: relu([out | src] @ m1w + m1b) @ m2w + m2b
  for (int j = t; j < DD; j += 256) {
    float acc = A.m1b[j];
    for (int x = 0; x < QDIM; x++) acc += s_o2[x] * A.m1w[(size_t)x * DD + j];
    for (int x = 0; x < DD; x++) acc += s_src[x] * A.m1w[(size_t)(QDIM + x) * DD + j];
    s_m1[j] = fmaxf(acc, 0.f);
  }
  __syncthreads();
  for (int j = t; j < DD; j += 256) {
    float acc = A.m2b[j];
    for (int x = 0; x < DD; x++) acc += s_m1[x] * A.m2w[(size_t)x * DD + j];
    A.out[(size_t)i * DD + j] = acc;
  }
}

// ---------------- launch ----------------
extern "C" void kernel_launch(void* const* d_in, const int* in_sizes, int n_in,
                              void* d_out, int out_size, void* d_ws, size_t ws_size,
                              hipStream_t stream) {
  const float* node_features = (const float*)d_in[0];
  const float* edge_features = (const float*)d_in[1];
  const float* memory        = (const float*)d_in[2];
  const float* last_update   = (const float*)d_in[3];
  const float* time_w        = (const float*)d_in[4];
  const float* time_b        = (const float*)d_in[5];
  const float* num_w1 = (const float*)d_in[6];
  const float* num_b1 = (const float*)d_in[7];
  const float* num_w2 = (const float*)d_in[8];
  const float* num_b2 = (const float*)d_in[9];
  const float* msg_w1 = (const float*)d_in[10];
  const float* msg_b1 = (const float*)d_in[11];
  const float* msg_w2 = (const float*)d_in[12];
  const float* msg_b2 = (const float*)d_in[13];
  const float* gru_wih = (const float*)d_in[14];
  const float* gru_whh = (const float*)d_in[15];
  const float* gru_bih = (const float*)d_in[16];
  const float* gru_bhh = (const float*)d_in[17];
  const float* att_wq = (const float*)d_in[18];
  const float* att_wk = (const float*)d_in[19];
  const float* att_wv = (const float*)d_in[20];
  const float* att_bq = (const float*)d_in[21];
  const float* att_bk = (const float*)d_in[22];
  const float* att_bv = (const float*)d_in[23];
  const float* att_wo = (const float*)d_in[24];
  const float* att_bo = (const float*)d_in[25];
  const float* mrg_w1 = (const float*)d_in[26];
  const float* mrg_b1 = (const float*)d_in[27];
  const float* mrg_w2 = (const float*)d_in[28];
  const float* mrg_b2 = (const float*)d_in[29];
  const float* edge_times = (const float*)d_in[30];
  const float* num_conn   = (const float*)d_in[31];
  const float* n1_et = (const float*)d_in[32];
  const float* n2_et = (const float*)d_in[33];
  const int* src = (const int*)d_in[34];
  const int* dst = (const int*)d_in[35];
  const int* neg = (const int*)d_in[36];
  const int* edge_idxs = (const int*)d_in[37];
  const int* n1_nb   = (const int*)d_in[38];
  const int* n1_eidx = (const int*)d_in[39];
  const int* n2_nb   = (const int*)d_in[40];
  const int* n2_eidx = (const int*)d_in[41];

  // ws layout: map[N] int | upd[2B*D] | src_conv[3B*D] | neigh1[3B*K*D]  (~8 MB)
  char* ws = (char*)d_ws;
  int* map = (int*)ws;
  float* upd = (float*)(ws + (size_t)NN * sizeof(int));
  float* src_conv = upd + (size_t)2 * BB * DD;
  float* neigh1 = src_conv + (size_t)3 * BB * DD;

  fill_map<<<(NN + 255) / 256, 256, 0, stream>>>(map);
  set_map<<<(BB + 63) / 64, 64, 0, stream>>>(map, src, dst);
  msg_gru<<<2 * BB, 256, 0, stream>>>(
      memory, edge_features, last_update, time_w, time_b,
      num_w1, num_b1, num_w2, num_b2, msg_w1, msg_b1, msg_w2, msg_b2,
      gru_wih, gru_whh, gru_bih, gru_bhh, edge_times, num_conn,
      src, dst, edge_idxs, upd);

  AttnArgs A;
  A.node_features = node_features; A.memory = memory; A.upd = upd; A.map = map;
  A.edge_features = edge_features; A.time_w = time_w; A.time_b = time_b;
  A.edge_times = edge_times; A.src = src; A.dst = dst; A.neg = neg;
  A.wq = att_wq; A.wk = att_wk; A.wv = att_wv;
  A.bq = att_bq; A.bk = att_bk; A.bv = att_bv;
  A.wo = att_wo; A.bo = att_bo;
  A.m1w = mrg_w1; A.m1b = mrg_b1; A.m2w = mrg_w2; A.m2b = mrg_b2;
  A.center_ids = nullptr; A.src_conv_in = nullptr; A.neigh_in = nullptr;

  AttnArgs A1 = A;   // 1-hop neighbor embeddings (dominant: 9000 blocks)
  A1.nb = n2_nb; A1.eidx = n2_eidx; A1.et = n2_et; A1.center_ids = n1_nb; A1.out = neigh1;
  attn_kernel<1><<<3 * BB * KK, 256, 0, stream>>>(A1);

  AttnArgs A0 = A;   // target-node layer-1 embeddings
  A0.nb = n1_nb; A0.eidx = n1_eidx; A0.et = n1_et; A0.out = src_conv;
  attn_kernel<0><<<3 * BB, 256, 0, stream>>>(A0);

  AttnArgs A2 = A;   // layer-2 aggregation -> output
  A2.wq = att_wq + QDIM * QDIM; A2.wk = att_wk + KDIM * QDIM; A2.wv = att_wv + KDIM * QDIM;
  A2.bq = att_bq + QDIM; A2.bk = att_bk + QDIM; A2.bv = att_bv + QDIM;
  A2.wo = att_wo + QDIM * QDIM; A2.bo = att_bo + QDIM;
  A2.m1w = mrg_w1 + KDIM * DD; A2.m1b = mrg_b1 + DD;
  A2.m2w = mrg_w2 + DD * DD;   A2.m2b = mrg_b2 + DD;
  A2.nb = n1_nb; A2.eidx = n1_eidx; A2.et = n1_et;
  A2.src_conv_in = src_conv; A2.neigh_in = neigh1; A2.out = (float*)d_out;
  attn_kernel<2><<<3 * BB, 256, 0, stream>>>(A2);
}

// Round 3
// 1380.700 us; speedup vs baseline: 4.1512x; 4.1512x over previous
//
#include <hip/hip_runtime.h>
#include <math.h>

#define NN 200000
#define EE 300000
#define BB 300
#define KK 10
#define DD 172
#define R0T 9900        // layer-0 batch rows (900 targets + 9000 hop-1 centers)
#define R0P 9984        // padded to 128
#define CH 1024         // nodes per layer-0 chunk (10 chunks)
#define NCH 10
#define KIN_K 576       // 516 padded to mult of 64
#define QIN_K 384       // 344 padded
#define H_K 192         // 172 padded
#define KVN 688         // wk|wv concat cols
#define KVNP 768        // padded Bt rows

typedef short bfrag __attribute__((ext_vector_type(8)));
typedef float f4 __attribute__((ext_vector_type(4)));

__device__ inline unsigned short f2b(float f) {
  unsigned int u = __builtin_bit_cast(unsigned int, f);
  u += 0x7fffu + ((u >> 16) & 1u);
  return (unsigned short)(u >> 16);
}
__device__ inline float b2f(unsigned short s) {
  unsigned int u = ((unsigned int)s) << 16;
  return __builtin_bit_cast(float, u);
}

// ---------------- map ----------------
__global__ __launch_bounds__(256) void fill_map(int* map) {
  int i = blockIdx.x * 256 + threadIdx.x;
  if (i < NN) map[i] = -1;
}
__global__ __launch_bounds__(64) void set_map(int* map, const int* src, const int* dst) {
  int i = blockIdx.x * 64 + threadIdx.x;
  if (i < BB) { map[src[i]] = i; map[dst[i]] = BB + i; }
}

// ---------------- message + GRU memory update (unchanged, passed R1) ----------------
#define RAWD 689
#define RAWH 344
#define MSGD 100
__global__ __launch_bounds__(256) void msg_gru(
    const float* memory, const float* edge_features, const float* last_update,
    const float* time_w, const float* time_b,
    const float* num_w1, const float* num_b1, const float* num_w2, const float* num_b2,
    const float* msg_w1, const float* msg_b1, const float* msg_w2, const float* msg_b2,
    const float* gru_wih, const float* gru_whh, const float* gru_bih, const float* gru_bhh,
    const float* edge_times, const float* num_conn,
    const int* src, const int* dst, const int* edge_idxs,
    float* upd) {
  __shared__ float s_raw[RAWD];
  __shared__ float s_h1[RAWH];
  __shared__ float s_msg[MSGD];
  __shared__ float s_gi[3 * DD];
  __shared__ float s_gh[3 * DD];
  const int r = blockIdx.x;
  const int e = (r < BB) ? r : r - BB;
  const int a = (r < BB) ? src[e] : dst[e];
  const int b = (r < BB) ? dst[e] : src[e];
  const int t = threadIdx.x;
  const int ei = edge_idxs[e];
  const float dt = edge_times[e] - last_update[a];
  for (int d = t; d < DD; d += 256) {
    s_raw[d]          = memory[(size_t)a * DD + d];
    s_raw[DD + d]     = memory[(size_t)b * DD + d];
    s_raw[2 * DD + d] = edge_features[(size_t)ei * DD + d];
    s_raw[3 * DD + d] = cosf(dt * time_w[d] + time_b[d]);
  }
  if (t == 0) {
    float ne = fmaxf(num_conn[e] * num_w1[0] + num_b1[0], 0.f) * num_w2[0] + num_b2[0];
    s_raw[4 * DD] = ne;
  }
  __syncthreads();
  for (int j = t; j < RAWH; j += 256) {
    float acc = msg_b1[j];
    for (int i = 0; i < RAWD; i++) acc += s_raw[i] * msg_w1[(size_t)i * RAWH + j];
    s_h1[j] = fmaxf(acc, 0.f);
  }
  __syncthreads();
  for (int j = t; j < MSGD; j += 256) {
    float acc = msg_b2[j];
    for (int i = 0; i < RAWH; i++) acc += s_h1[i] * msg_w2[(size_t)i * MSGD + j];
    s_msg[j] = acc;
  }
  __syncthreads();
  for (int j = t; j < 3 * DD; j += 256) {
    float gi = gru_bih[j];
    for (int k = 0; k < MSGD; k++) gi += s_msg[k] * gru_wih[(size_t)j * MSGD + k];
    s_gi[j] = gi;
    float gh = gru_bhh[j];
    for (int k = 0; k < DD; k++) gh += s_raw[k] * gru_whh[(size_t)j * DD + k];
    s_gh[j] = gh;
  }
  __syncthreads();
  for (int d = t; d < DD; d += 256) {
    float rg = 1.f / (1.f + expf(-(s_gi[d] + s_gh[d])));
    float z  = 1.f / (1.f + expf(-(s_gi[DD + d] + s_gh[DD + d])));
    float nn = tanhf(s_gi[2 * DD + d] + rg * s_gh[2 * DD + d]);
    upd[(size_t)r * DD + d] = (1.f - z) * nn + z * s_raw[d];
  }
}

// ---------------- weight prep: transpose to [N][K] bf16, zero-padded ----------------
#define S_KV  (2*KVNP*KIN_K)
#define S_WQ  (2*QIN_K*QIN_K)
#define S_M1  (2*256*KIN_K)
#define S_M2  (2*256*H_K)
#define S_KVB (2*KVN)
__global__ __launch_bounds__(256) void prep_weights(
    const float* wk, const float* wv, const float* wq, const float* wo,
    const float* m1, const float* m2, const float* bk, const float* bv,
    unsigned short* wkv_t, unsigned short* wq_t, unsigned short* wo_t,
    unsigned short* wm1_t, unsigned short* wm2_t, float* kvb) {
  long idx = (long)blockIdx.x * 256 + threadIdx.x;
  if (idx < S_KV) {
    int l = idx / (KVNP * KIN_K); int r = idx % (KVNP * KIN_K);
    int n = r / KIN_K, k = r % KIN_K;
    float v = 0.f;
    if (k < 516 && n < KVN)
      v = (n < 344) ? wk[(size_t)l*516*344 + (size_t)k*344 + n]
                    : wv[(size_t)l*516*344 + (size_t)k*344 + (n-344)];
    wkv_t[idx] = f2b(v); return;
  }
  idx -= S_KV;
  if (idx < S_WQ) {
    int l = idx / (QIN_K*QIN_K); int r = idx % (QIN_K*QIN_K);
    int n = r / QIN_K, k = r % QIN_K;
    float v = (k < 344 && n < 344) ? wq[(size_t)l*344*344 + (size_t)k*344 + n] : 0.f;
    wq_t[idx] = f2b(v); return;
  }
  idx -= S_WQ;
  if (idx < S_WQ) {
    int l = idx / (QIN_K*QIN_K); int r = idx % (QIN_K*QIN_K);
    int n = r / QIN_K, k = r % QIN_K;
    float v = (k < 344 && n < 344) ? wo[(size_t)l*344*344 + (size_t)k*344 + n] : 0.f;
    wo_t[idx] = f2b(v); return;
  }
  idx -= S_WQ;
  if (idx < S_M1) {
    int l = idx / (256*KIN_K); int r = idx % (256*KIN_K);
    int n = r / KIN_K, k = r % KIN_K;
    float v = (k < 516 && n < 172) ? m1[(size_t)l*516*172 + (size_t)k*172 + n] : 0.f;
    wm1_t[idx] = f2b(v); return;
  }
  idx -= S_M1;
  if (idx < S_M2) {
    int l = idx / (256*H_K); int r = idx % (256*H_K);
    int n = r / H_K, k = r % H_K;
    float v = (k < 172 && n < 172) ? m2[(size_t)l*172*172 + (size_t)k*172 + n] : 0.f;
    wm2_t[idx] = f2b(v); return;
  }
  idx -= S_M2;
  if (idx < S_KVB) {
    int l = idx / KVN; int c = idx % KVN;
    kvb[idx] = (c < 344) ? bk[(size_t)l*344 + c] : bv[(size_t)l*344 + (c-344)];
  }
}

// ---------------- 128x128 bf16 MFMA GEMM: C = A[M x Kpad] * Bt[N x Kpad]^T + bias ----------------
template<bool OBF, bool RELU>
__global__ __launch_bounds__(256) void gemm128(
    const unsigned short* __restrict__ A, int lda,
    const unsigned short* __restrict__ Bt, int ldb,
    const float* __restrict__ bias,
    void* __restrict__ Cv, int ldc, int M, int N, int Kpad) {
  // __align__(16): the uint4 / short8 casts below require a 16B-aligned LDS base.
  __shared__ __align__(16) unsigned short As[128][72];  // 72*2=144B row stride (16B mult)
  __shared__ __align__(16) unsigned short Bs[128][72];
  const int tid = threadIdx.x;
  const int lane = tid & 63, w = tid >> 6;
  const int rbase = (w >> 1) * 64, cbase = (w & 1) * 64;
  const int fr = lane & 15, fq = lane >> 4;
  const size_t Arow0 = (size_t)blockIdx.x * 128;
  const size_t Brow0 = (size_t)blockIdx.y * 128;
  f4 acc[4][4];
#pragma unroll
  for (int a = 0; a < 4; a++)
#pragma unroll
    for (int b = 0; b < 4; b++)
#pragma unroll
      for (int r = 0; r < 4; r++) acc[a][b][r] = 0.f;

  const int srow = tid >> 3, sch = tid & 7;
  for (int k0 = 0; k0 < Kpad; k0 += 64) {
#pragma unroll
    for (int p = 0; p < 4; p++) {
      int row = srow + p * 32;
      *(uint4*)&As[row][sch * 8] = *(const uint4*)(A + (Arow0 + row) * lda + k0 + sch * 8);
      *(uint4*)&Bs[row][sch * 8] = *(const uint4*)(Bt + (Brow0 + row) * ldb + k0 + sch * 8);
    }
    __syncthreads();
#pragma unroll
    for (int s = 0; s < 2; s++) {
      bfrag a[4], b[4];
#pragma unroll
      for (int mt = 0; mt < 4; mt++) a[mt] = *(const bfrag*)&As[rbase + mt*16 + fr][s*32 + fq*8];
#pragma unroll
      for (int nt = 0; nt < 4; nt++) b[nt] = *(const bfrag*)&Bs[cbase + nt*16 + fr][s*32 + fq*8];
#pragma unroll
      for (int mt = 0; mt < 4; mt++)
#pragma unroll
        for (int nt = 0; nt < 4; nt++)
          acc[mt][nt] = __builtin_amdgcn_mfma_f32_16x16x32_bf16(a[mt], b[nt], acc[mt][nt], 0, 0, 0);
    }
    __syncthreads();
  }
#pragma unroll
  for (int mt = 0; mt < 4; mt++) {
#pragma unroll
    for (int nt = 0; nt < 4; nt++) {
      int gc = (int)Brow0 + cbase + nt * 16 + fr;
      float bias_v = (bias != nullptr && gc < N) ? bias[gc] : 0.f;
#pragma unroll
      for (int r = 0; r < 4; r++) {
        int gr = (int)Arow0 + rbase + mt * 16 + fq * 4 + r;
        if (gr < M && gc < N) {
          float v = acc[mt][nt][r] + bias_v;
          if (RELU) v = fmaxf(v, 0.f);
          if (OBF) ((unsigned short*)Cv)[(size_t)gr * ldc + gc] = f2b(v);
          else     ((float*)Cv)[(size_t)gr * ldc + gc] = v;
        }
      }
    }
  }
}

// ---------------- builders ----------------
__global__ __launch_bounds__(256) void build_qin0(
    const int* src, const int* dst, const int* neg, const int* n1_nb,
    const float* memory, const float* upd, const int* map, const float* nf,
    const float* time_b, unsigned short* qin) {
  int i = blockIdx.x, t = threadIdx.x;
  int node = (i < BB) ? src[i] : (i < 2*BB) ? dst[i-BB] : (i < 3*BB) ? neg[i-2*BB] : n1_nb[i-3*BB];
  int m = map[node];
  const float* mrow = (m >= 0) ? upd + (size_t)m * DD : memory + (size_t)node * DD;
  for (int c = t; c < QIN_K; c += 256) {
    unsigned short v;
    if (c < DD) v = f2b(mrow[c] + nf[(size_t)node * DD + c]);
    else if (c < 2*DD) v = f2b(cosf(time_b[c - DD]));
    else v = 0;
    qin[(size_t)i * QIN_K + c] = v;
  }
}

__global__ __launch_bounds__(256) void build_kin0(
    int base, const int* n1_nb, const int* n1_ei, const float* n1_et,
    const int* n2_nb, const int* n2_ei, const float* n2_et,
    const float* edge_times, const float* memory, const float* upd, const int* map,
    const float* nf, const float* ef, const float* time_w, const float* time_b,
    unsigned short* kin_c) {
  int ib = blockIdx.x, t = threadIdx.x;
  int i = base + ib;
  __shared__ int s_nb[KK]; __shared__ int s_ei[KK]; __shared__ float s_et[KK];
  float ts;
  if (i < 3*BB) {
    if (t < KK) { s_nb[t] = n1_nb[(size_t)i*KK+t]; s_ei[t] = n1_ei[(size_t)i*KK+t]; s_et[t] = n1_et[(size_t)i*KK+t]; }
    ts = edge_times[i % BB];
  } else {
    int j = i - 3*BB;
    if (t < KK) { s_nb[t] = n2_nb[(size_t)j*KK+t]; s_ei[t] = n2_ei[(size_t)j*KK+t]; s_et[t] = n2_et[(size_t)j*KK+t]; }
    ts = edge_times[(j / KK) % BB];
  }
  __syncthreads();
  for (int f = t; f < KK * KIN_K; f += 256) {
    int k = f / KIN_K, c = f - k * KIN_K;
    float v;
    if (c < DD) {
      int nb = s_nb[k]; int m = map[nb];
      v = ((m >= 0) ? upd[(size_t)m*DD + c] : memory[(size_t)nb*DD + c]) + nf[(size_t)nb*DD + c];
    } else if (c < 2*DD) {
      v = ef[(size_t)s_ei[k]*DD + (c - DD)];
    } else if (c < 3*DD) {
      int d = c - 2*DD;
      v = cosf((ts - s_et[k]) * time_w[d] + time_b[d]);
    } else v = 0.f;
    kin_c[(size_t)(ib * KK + k) * KIN_K + c] = f2b(v);
  }
}

__global__ __launch_bounds__(256) void build_qin1(
    const unsigned short* conv0, const float* time_b, unsigned short* qin1) {
  int i = blockIdx.x, t = threadIdx.x;
  for (int c = t; c < QIN_K; c += 256) {
    unsigned short v;
    if (c < DD) v = conv0[(size_t)i * DD + c];
    else if (c < 2*DD) v = f2b(cosf(time_b[c - DD]));
    else v = 0;
    qin1[(size_t)i * QIN_K + c] = v;
  }
}

__global__ __launch_bounds__(256) void build_kin1(
    const unsigned short* conv0, const float* ef, const float* time_w, const float* time_b,
    const float* edge_times, const int* n1_ei, const float* n1_et, unsigned short* kin1) {
  int i = blockIdx.x, t = threadIdx.x;
  float ts = edge_times[i % BB];
  __shared__ int s_ei[KK]; __shared__ float s_et[KK];
  if (t < KK) { s_ei[t] = n1_ei[(size_t)i*KK+t]; s_et[t] = n1_et[(size_t)i*KK+t]; }
  __syncthreads();
  for (int f = t; f < KK * KIN_K; f += 256) {
    int k = f / KIN_K, c = f - k * KIN_K;
    unsigned short v;
    if (c < DD) v = conv0[(size_t)(3*BB + i*KK + k) * DD + c];
    else if (c < 2*DD) v = f2b(ef[(size_t)s_ei[k]*DD + (c - DD)]);
    else if (c < 3*DD) { int d = c - 2*DD; v = f2b(cosf((ts - s_et[k]) * time_w[d] + time_b[d])); }
    else v = 0;
    kin1[(size_t)(i * KK + k) * KIN_K + c] = v;
  }
}

// ---------------- scores / softmax / attn@V (Q, KV in bf16) ----------------
__global__ __launch_bounds__(256) void attn_combine(
    const unsigned short* Q /*ld 344*/, const unsigned short* KV /*chunk rows, ld 688*/,
    const int* nbA, const int* nbB, int split,
    unsigned short* Oin /*global rows, ld 384*/, int base) {
  __shared__ float s_q[2*DD];
  __shared__ float s_part[20][8];
  __shared__ float s_att[2][KK];
  __shared__ int s_nb[KK];
  int ib = blockIdx.x, t = threadIdx.x;
  int i = base + ib;
  const int* nbp = (i < split) ? nbA + (size_t)i * KK : nbB + (size_t)(i - split) * KK;
  if (t < KK) s_nb[t] = nbp[t];
  for (int c = t; c < 2*DD; c += 256) s_q[c] = b2f(Q[(size_t)i * 2*DD + c]);
  __syncthreads();
  if (t < 160) {
    int p = t >> 3, sub = t & 7;
    int h = p / KK, kk = p - h * KK;
    const unsigned short* krow = KV + (size_t)(ib * KK + kk) * KVN + h * DD;
    float acc = 0.f;
    for (int d = sub; d < DD; d += 8) acc += s_q[h*DD + d] * b2f(krow[d]);
    s_part[p][sub] = acc;
  }
  __syncthreads();
  if (t < 20) {
    float sc = 0.f;
    for (int s = 0; s < 8; s++) sc += s_part[t][s];
    sc *= 0.0762492852f;  // 1/sqrt(172)
    int kk = t % KK;
    if (s_nb[kk] == 0) sc = -1e9f;
    s_part[t][0] = sc;
  }
  __syncthreads();
  if (t < 2) {
    float mx = -1e30f;
    for (int kk = 0; kk < KK; kk++) mx = fmaxf(mx, s_part[t*KK + kk][0]);
    float e[KK], sum = 0.f;
    for (int kk = 0; kk < KK; kk++) { e[kk] = expf(s_part[t*KK + kk][0] - mx); sum += e[kk]; }
    float inv = 1.f / sum;
    for (int kk = 0; kk < KK; kk++) s_att[t][kk] = e[kk] * inv;
  }
  __syncthreads();
  for (int c = t; c < QIN_K; c += 256) {
    float v = 0.f;
    if (c < 2*DD) {
      int h = c / DD;
      const unsigned short* vb = KV + (size_t)(ib * KK) * KVN + 344 + c;
#pragma unroll
      for (int kk = 0; kk < KK; kk++) v += s_att[h][kk] * b2f(vb[(size_t)kk * KVN]);
    }
    Oin[(size_t)i * QIN_K + c] = f2b(v);
  }
}

// mrgA row = [mask? 0 : o2 (344) | src_feat (172) | 0 pad], bf16 stride 576
__global__ __launch_bounds__(256) void build_mrgA(
    const unsigned short* o2 /*ld 384*/, const int* nbA, const int* nbB, int split,
    const unsigned short* srcf, int ld_src, unsigned short* mrgA) {
  int i = blockIdx.x, t = threadIdx.x;
  const int* nbp = (i < split) ? nbA + (size_t)i * KK : nbB + (size_t)(i - split) * KK;
  __shared__ int allm;
  if (t == 0) {
    int a = 1;
    for (int k = 0; k < KK; k++) if (nbp[k] != 0) a = 0;
    allm = a;
  }
  __syncthreads();
  for (int c = t; c < KIN_K; c += 256) {
    unsigned short v;
    if (c < 2*DD) v = allm ? (unsigned short)0 : o2[(size_t)i * QIN_K + c];
    else if (c < 3*DD) v = srcf[(size_t)i * ld_src + (c - 2*DD)];
    else v = 0;
    mrgA[(size_t)i * KIN_K + c] = v;
  }
}

// ---------------- launch ----------------
extern "C" void kernel_launch(void* const* d_in, const int* in_sizes, int n_in,
                              void* d_out, int out_size, void* d_ws, size_t ws_size,
                              hipStream_t stream) {
  const float* node_features = (const float*)d_in[0];
  const float* edge_features = (const float*)d_in[1];
  const float* memory        = (const float*)d_in[2];
  const float* last_update   = (const float*)d_in[3];
  const float* time_w        = (const float*)d_in[4];
  const float* time_b        = (const float*)d_in[5];
  const float* num_w1 = (const float*)d_in[6];
  const float* num_b1 = (const float*)d_in[7];
  const float* num_w2 = (const float*)d_in[8];
  const float* num_b2 = (const float*)d_in[9];
  const float* msg_w1 = (const float*)d_in[10];
  const float* msg_b1 = (const float*)d_in[11];
  const float* msg_w2 = (const float*)d_in[12];
  const float* msg_b2 = (const float*)d_in[13];
  const float* gru_wih = (const float*)d_in[14];
  const float* gru_whh = (const float*)d_in[15];
  const float* gru_bih = (const float*)d_in[16];
  const float* gru_bhh = (const float*)d_in[17];
  const float* att_wq = (const float*)d_in[18];
  const float* att_wk = (const float*)d_in[19];
  const float* att_wv = (const float*)d_in[20];
  const float* att_bq = (const float*)d_in[21];
  const float* att_bk = (const float*)d_in[22];
  const float* att_bv = (const float*)d_in[23];
  const float* att_wo = (const float*)d_in[24];
  const float* att_bo = (const float*)d_in[25];
  const float* mrg_w1 = (const float*)d_in[26];
  const float* mrg_b1 = (const float*)d_in[27];
  const float* mrg_w2 = (const float*)d_in[28];
  const float* mrg_b2 = (const float*)d_in[29];
  const float* edge_times = (const float*)d_in[30];
  const float* num_conn   = (const float*)d_in[31];
  const float* n1_et = (const float*)d_in[32];
  const float* n2_et = (const float*)d_in[33];
  const int* src = (const int*)d_in[34];
  const int* dst = (const int*)d_in[35];
  const int* neg = (const int*)d_in[36];
  const int* edge_idxs = (const int*)d_in[37];
  const int* n1_nb   = (const int*)d_in[38];
  const int* n1_eidx = (const int*)d_in[39];
  const int* n2_nb   = (const int*)d_in[40];
  const int* n2_eidx = (const int*)d_in[41];

  // ---- workspace: persistent ~30.6MB + one overlaid transient region ~27.6MB = ~58.2MB ----
  char* ws = (char*)d_ws;
  size_t off = 0;
  auto alloc = [&](size_t bytes) -> char* {
    char* p = ws + off;
    off = (off + bytes + 255) & ~(size_t)255;
    return p;
  };
  int* map = (int*)alloc((size_t)NN * 4);
  float* upd = (float*)alloc((size_t)2 * BB * DD * 4);
  unsigned short* wkv_t = (unsigned short*)alloc((size_t)S_KV * 2);
  unsigned short* wq_t  = (unsigned short*)alloc((size_t)S_WQ * 2);
  unsigned short* wo_t  = (unsigned short*)alloc((size_t)S_WQ * 2);
  unsigned short* wm1_t = (unsigned short*)alloc((size_t)S_M1 * 2);
  unsigned short* wm2_t = (unsigned short*)alloc((size_t)S_M2 * 2);
  float* kvb = (float*)alloc((size_t)S_KVB * 4);
  unsigned short* qin0  = (unsigned short*)alloc((size_t)R0P * QIN_K * 2);  // q_in + src feat
  unsigned short* q0    = (unsigned short*)alloc((size_t)R0P * 344 * 2);    // Q bf16
  unsigned short* o_in0 = (unsigned short*)alloc((size_t)R0P * QIN_K * 2);  // attn out (pre-Wo)
  unsigned short* conv0 = (unsigned short*)alloc((size_t)R0P * DD * 2);     // layer-0 output

  // transient region (phases are stream-serialized; later phases may overwrite earlier)
  char* Tbase = ws + off;
  // phase chunk-KV:
  unsigned short* kin_c = (unsigned short*)Tbase;                                      // CH*10*576*2
  unsigned short* kv_c  = (unsigned short*)(Tbase + (((size_t)CH*KK*KIN_K*2 + 255) & ~(size_t)255));
  // phase merge (after all chunks):
  size_t moff = 0;
  auto malloc_ = [&](size_t bytes) -> char* {
    char* p = Tbase + moff; moff = (moff + bytes + 255) & ~(size_t)255; return p;
  };
  unsigned short* o2_0  = (unsigned short*)malloc_((size_t)R0P * QIN_K * 2);
  unsigned short* mrgA0 = (unsigned short*)malloc_((size_t)R0P * KIN_K * 2);
  unsigned short* h0    = (unsigned short*)malloc_((size_t)R0P * H_K * 2);
  // phase layer-1 (after merge writes conv0, which is persistent):
  size_t loff = 0;
  auto lalloc = [&](size_t bytes) -> char* {
    char* p = Tbase + loff; loff = (loff + bytes + 255) & ~(size_t)255; return p;
  };
  unsigned short* qin1 = (unsigned short*)lalloc((size_t)1024 * QIN_K * 2);
  unsigned short* kin1 = (unsigned short*)lalloc((size_t)9088 * KIN_K * 2);
  unsigned short* q1   = (unsigned short*)lalloc((size_t)1024 * 344 * 2);
  unsigned short* kv1  = (unsigned short*)lalloc((size_t)9088 * KVN * 2);
  unsigned short* o_in1 = (unsigned short*)lalloc((size_t)1024 * QIN_K * 2);
  unsigned short* o2_1  = (unsigned short*)lalloc((size_t)1024 * QIN_K * 2);
  unsigned short* mrgA1 = (unsigned short*)lalloc((size_t)1024 * KIN_K * 2);
  unsigned short* h1    = (unsigned short*)lalloc((size_t)1024 * H_K * 2);

  // ---- phase A: map + memory update + weight prep ----
  fill_map<<<(NN + 255) / 256, 256, 0, stream>>>(map);
  set_map<<<(BB + 63) / 64, 64, 0, stream>>>(map, src, dst);
  msg_gru<<<2 * BB, 256, 0, stream>>>(
      memory, edge_features, last_update, time_w, time_b,
      num_w1, num_b1, num_w2, num_b2, msg_w1, msg_b1, msg_w2, msg_b2,
      gru_wih, gru_whh, gru_bih, gru_bhh, edge_times, num_conn,
      src, dst, edge_idxs, upd);
  {
    long total = (long)S_KV + 2 * S_WQ + S_M1 + S_M2 + S_KVB;
    prep_weights<<<(int)((total + 255) / 256), 256, 0, stream>>>(
        att_wk, att_wv, att_wq, att_wo, mrg_w1, mrg_w2, att_bk, att_bv,
        wkv_t, wq_t, wo_t, wm1_t, wm2_t, kvb);
  }

  // ---- layer-0: q_in + Q ----
  build_qin0<<<R0T, 256, 0, stream>>>(src, dst, neg, n1_nb, memory, upd, map,
                                      node_features, time_b, qin0);
  gemm128<true, false><<<dim3(R0P/128, 3), 256, 0, stream>>>(
      qin0, QIN_K, wq_t, QIN_K, att_bq, q0, 344, R0T, 344, QIN_K);

  // ---- layer-0 KV + attention, chunked ----
  for (int c = 0; c < NCH; c++) {
    int base = c * CH;
    int nN = R0T - base; if (nN > CH) nN = CH;
    if (nN <= 0) break;
    int mrows = nN * KK;
    build_kin0<<<nN, 256, 0, stream>>>(base, n1_nb, n1_eidx, n1_et,
        n2_nb, n2_eidx, n2_et, edge_times, memory, upd, map,
        node_features, edge_features, time_w, time_b, kin_c);
    gemm128<true, false><<<dim3((mrows + 127)/128, 6), 256, 0, stream>>>(
        kin_c, KIN_K, wkv_t, KIN_K, kvb, kv_c, KVN, mrows, KVN, KIN_K);
    attn_combine<<<nN, 256, 0, stream>>>(q0, kv_c, n1_nb, n2_nb, 3*BB, o_in0, base);
  }

  // ---- layer-0 output projection + merge MLP ----
  gemm128<true, false><<<dim3(R0P/128, 3), 256, 0, stream>>>(
      o_in0, QIN_K, wo_t, QIN_K, att_bo, o2_0, QIN_K, R0T, 344, QIN_K);
  build_mrgA<<<R0T, 256, 0, stream>>>(o2_0, n1_nb, n2_nb, 3*BB, qin0, QIN_K, mrgA0);
  gemm128<true, true><<<dim3(R0P/128, 2), 256, 0, stream>>>(
      mrgA0, KIN_K, wm1_t, KIN_K, mrg_b1, h0, H_K, R0T, 172, KIN_K);
  gemm128<true, false><<<dim3(R0P/128, 2), 256, 0, stream>>>(
      h0, H_K, wm2_t, H_K, mrg_b2, conv0, DD, R0T, 172, H_K);

  // ---- layer-1 (900 nodes) ----
  build_qin1<<<3*BB, 256, 0, stream>>>(conv0, time_b, qin1);
  build_kin1<<<3*BB, 256, 0, stream>>>(conv0, edge_features, time_w, time_b,
                                       edge_times, n1_eidx, n1_et, kin1);
  gemm128<true, false><<<dim3(8, 3), 256, 0, stream>>>(
      qin1, QIN_K, wq_t + (size_t)QIN_K*QIN_K, QIN_K, att_bq + 344, q1, 344, 3*BB, 344, QIN_K);
  gemm128<true, false><<<dim3(71, 6), 256, 0, stream>>>(
      kin1, KIN_K, wkv_t + (size_t)KVNP*KIN_K, KIN_K, kvb + KVN, kv1, KVN, 3*BB*KK, KVN, KIN_K);
  attn_combine<<<3*BB, 256, 0, stream>>>(q1, kv1, n1_nb, n1_nb, 3*BB, o_in1, 0);
  gemm128<true, false><<<dim3(8, 3), 256, 0, stream>>>(
      o_in1, QIN_K, wo_t + (size_t)QIN_K*QIN_K, QIN_K, att_bo + 344, o2_1, QIN_K, 3*BB, 344, QIN_K);
  build_mrgA<<<3*BB, 256, 0, stream>>>(o2_1, n1_nb, n1_nb, 3*BB, conv0, DD, mrgA1);
  gemm128<true, true><<<dim3(8, 2), 256, 0, stream>>>(
      mrgA1, KIN_K, wm1_t + (size_t)256*KIN_K, KIN_K, mrg_b1 + 172, h1, H_K, 3*BB, 172, KIN_K);
  gemm128<false, false><<<dim3(8, 2), 256, 0, stream>>>(
      h1, H_K, wm2_t + (size_t)256*H_K, H_K, mrg_b2 + 172, (float*)d_out, DD, 3*BB, 172, H_K);
}

// Round 4
// 1044.116 us; speedup vs baseline: 5.4894x; 1.3224x over previous
//
#include <hip/hip_runtime.h>
#include <math.h>

#define NN 200000
#define BB 300
#define KK 10
#define DD 172
#define R0T 9900        // layer-0 rows: 900 targets + 9000 hop-1 centers
#define R0P 9984        // padded to 128
#define L1P 1024        // 900 padded
#define QIN_K 384       // 344 padded
#define KIN_K 576       // 516 padded (merge A width)
#define H_K 192         // 172 padded
#define CK 1088         // 2*516 padded to 64-mult (c-vector / Mcat K)
#define QKN 1034        // qk cols: 2*516 + 2 qbk cols
#define QKLD 1040
#define GROWS 1152      // Gcat Bt rows (9 tiles)

typedef short bfrag __attribute__((ext_vector_type(8)));
typedef float f4 __attribute__((ext_vector_type(4)));

__device__ inline unsigned short f2b(float f) {
  unsigned int u = __builtin_bit_cast(unsigned int, f);
  u += 0x7fffu + ((u >> 16) & 1u);
  return (unsigned short)(u >> 16);
}
__device__ inline float b2f(unsigned short s) {
  unsigned int u = ((unsigned int)s) << 16;
  return __builtin_bit_cast(float, u);
}
__device__ inline float sigm(float x) { return 1.f / (1.f + expf(-x)); }

// ---------------- map ----------------
__global__ __launch_bounds__(256) void fill_map(int* map) {
  int i = blockIdx.x * 256 + threadIdx.x;
  if (i < NN) map[i] = -1;
}
__global__ __launch_bounds__(64) void set_map(int* map, const int* src, const int* dst) {
  int i = blockIdx.x * 64 + threadIdx.x;
  if (i < BB) { map[src[i]] = i; map[dst[i]] = BB + i; }
}

// ---------------- bf16 weight prep (slices/transposes, zero-padded) ----------------
#define SZ_WQH (2*2*384*192)
#define SZ_WKH (2*2*640*192)
#define SZ_WVH (2*2*640*192)
#define SZ_WOT (2*2*384*192)
#define SZ_M1  (2*256*576)
#define SZ_M2  (2*256*192)
#define SZ_MW1 (384*704)
#define SZ_MW2 (128*384)
#define SZ_GIH (640*128)
#define SZ_GHH (640*192)
__global__ __launch_bounds__(256) void prep_w(
    const float* wq, const float* wk, const float* wv, const float* wo,
    const float* m1, const float* m2, const float* mw1, const float* mw2,
    const float* gih, const float* ghh,
    unsigned short* wqh_b, unsigned short* wkh_b, unsigned short* wvh_b,
    unsigned short* woT_b, unsigned short* wm1_t, unsigned short* wm2_t,
    unsigned short* msgw1t, unsigned short* msgw2t,
    unsigned short* gruwih_b, unsigned short* gruwhh_b) {
  long idx = (long)blockIdx.x * 256 + threadIdx.x;
  if (idx < SZ_WQH) {  // wqh_b[l][h][y<384][d<192] = Wq[l][y][h*172+d]
    int l = idx / (2*384*192), r = idx % (2*384*192);
    int h = r / (384*192); r %= 384*192;
    int y = r / 192, d = r % 192;
    wqh_b[idx] = (y < 344 && d < 172) ? f2b(wq[(size_t)l*344*344 + (size_t)y*344 + h*172 + d]) : 0;
    return;
  }
  idx -= SZ_WQH;
  if (idx < SZ_WKH) {  // wkh_b[l][h][x<640][d<192] = Wk[l][x][h*172+d]
    int l = idx / (2*640*192), r = idx % (2*640*192);
    int h = r / (640*192); r %= 640*192;
    int x = r / 192, d = r % 192;
    wkh_b[idx] = (x < 516 && d < 172) ? f2b(wk[(size_t)l*516*344 + (size_t)x*344 + h*172 + d]) : 0;
    return;
  }
  idx -= SZ_WKH;
  if (idx < SZ_WVH) {
    int l = idx / (2*640*192), r = idx % (2*640*192);
    int h = r / (640*192); r %= 640*192;
    int x = r / 192, d = r % 192;
    wvh_b[idx] = (x < 516 && d < 172) ? f2b(wv[(size_t)l*516*344 + (size_t)x*344 + h*172 + d]) : 0;
    return;
  }
  idx -= SZ_WVH;
  if (idx < SZ_WOT) {  // woT_b[l][h][j<384][d<192] = Wo[l][h*172+d][j]
    int l = idx / (2*384*192), r = idx % (2*384*192);
    int h = r / (384*192); r %= 384*192;
    int j = r / 192, d = r % 192;
    woT_b[idx] = (j < 344 && d < 172) ? f2b(wo[(size_t)l*344*344 + (size_t)(h*172+d)*344 + j]) : 0;
    return;
  }
  idx -= SZ_WOT;
  if (idx < SZ_M1) {  // wm1_t[l][j<256][k<576] = m1[l][k][j]
    int l = idx / (256*576), r = idx % (256*576);
    int j = r / 576, k = r % 576;
    wm1_t[idx] = (j < 172 && k < 516) ? f2b(m1[(size_t)l*516*172 + (size_t)k*172 + j]) : 0;
    return;
  }
  idx -= SZ_M1;
  if (idx < SZ_M2) {  // wm2_t[l][j<256][k<192] = m2[l][k][j]
    int l = idx / (256*192), r = idx % (256*192);
    int j = r / 192, k = r % 192;
    wm2_t[idx] = (j < 172 && k < 172) ? f2b(m2[(size_t)l*172*172 + (size_t)k*172 + j]) : 0;
    return;
  }
  idx -= SZ_M2;
  if (idx < SZ_MW1) {  // msgw1t[j<384][k<704] = mw1[k][j]
    int j = idx / 704, k = idx % 704;
    msgw1t[idx] = (j < 344 && k < 689) ? f2b(mw1[(size_t)k*344 + j]) : 0;
    return;
  }
  idx -= SZ_MW1;
  if (idx < SZ_MW2) {  // msgw2t[j<128][k<384] = mw2[k][j]
    int j = idx / 384, k = idx % 384;
    msgw2t[idx] = (j < 100 && k < 344) ? f2b(mw2[(size_t)k*100 + j]) : 0;
    return;
  }
  idx -= SZ_MW2;
  if (idx < SZ_GIH) {  // gruwih_b[j<640][k<128] = gih[j][k]
    int j = idx / 128, k = idx % 128;
    gruwih_b[idx] = (j < 516 && k < 100) ? f2b(gih[(size_t)j*100 + k]) : 0;
    return;
  }
  idx -= SZ_GIH;
  if (idx < SZ_GHH) {  // gruwhh_b[j<640][k<192] = ghh[j][k]
    int j = idx / 192, k = idx % 192;
    gruwhh_b[idx] = (j < 516 && k < 172) ? f2b(ghh[(size_t)j*172 + k]) : 0;
    return;
  }
}

// fp32 bias folds + gvec rows of Gcat
// bqk[l][x<1032] = Wk_h @ bq_h ; bqk[l][1032+h] = bq_h . bk_h ; pad 0
// bvwo[l][j] = bv . Wo[:,j] + bo[j]
// Gcat[l][(1032+h)*384 + y] = bf16( sum_d Wq[y][h*172+d]*bk[h*172+d] )
#define SB_QK (2*QKLD)
#define SB_VO (2*344)
#define SB_GV (2*2*384)
__global__ __launch_bounds__(256) void prep_bias(
    const float* wq, const float* wk, const float* wo,
    const float* bq, const float* bk, const float* bv, const float* bo,
    float* bqk, float* bvwo, unsigned short* Gcat) {
  long idx = (long)blockIdx.x * 256 + threadIdx.x;
  if (idx < SB_QK) {
    int l = idx / QKLD, x = idx % QKLD;
    float acc = 0.f;
    if (x < 1032) {
      int h = x / 516, xx = x % 516;
      for (int d = 0; d < 172; d++)
        acc += wk[(size_t)l*516*344 + (size_t)xx*344 + h*172 + d] * bq[(size_t)l*344 + h*172 + d];
    } else if (x < 1034) {
      int h = x - 1032;
      for (int d = 0; d < 172; d++)
        acc += bq[(size_t)l*344 + h*172 + d] * bk[(size_t)l*344 + h*172 + d];
    }
    bqk[idx] = acc;
    return;
  }
  idx -= SB_QK;
  if (idx < SB_VO) {
    int l = idx / 344, j = idx % 344;
    float acc = bo[(size_t)l*344 + j];
    for (int c = 0; c < 344; c++)
      acc += bv[(size_t)l*344 + c] * wo[(size_t)l*344*344 + (size_t)c*344 + j];
    bvwo[idx] = acc;
    return;
  }
  idx -= SB_VO;
  if (idx < SB_GV) {
    int l = idx / (2*384), r = idx % (2*384);
    int h = r / 384, y = r % 384;
    float acc = 0.f;
    if (y < 344)
      for (int d = 0; d < 172; d++)
        acc += wq[(size_t)l*344*344 + (size_t)y*344 + h*172 + d] * bk[(size_t)l*344 + h*172 + d];
    Gcat[(size_t)l*GROWS*384 + (size_t)(1032+h)*384 + y] = (y < 344) ? f2b(acc) : 0;
    return;
  }
}

// ---------------- 128x128 bf16 MFMA GEMM: C = A[MxKpad] @ Bt[NxKpad]^T + bias ----------------
// Writes cols gc<Nz (value for gc<N, zero for N<=gc<Nz).
template<bool OBF, bool RELU>
__global__ __launch_bounds__(256) void gemm128(
    const unsigned short* __restrict__ A, int lda,
    const unsigned short* __restrict__ Bt, int ldb,
    const float* __restrict__ bias,
    void* __restrict__ Cv, int ldc, int M, int N, int Nz, int Kpad) {
  __shared__ __align__(16) unsigned short As[128][72];
  __shared__ __align__(16) unsigned short Bs[128][72];
  const int tid = threadIdx.x;
  const int lane = tid & 63, w = tid >> 6;
  const int rbase = (w >> 1) * 64, cbase = (w & 1) * 64;
  const int fr = lane & 15, fq = lane >> 4;
  const size_t Arow0 = (size_t)blockIdx.x * 128;
  const size_t Brow0 = (size_t)blockIdx.y * 128;
  f4 acc[4][4];
#pragma unroll
  for (int a = 0; a < 4; a++)
#pragma unroll
    for (int b = 0; b < 4; b++)
#pragma unroll
      for (int r = 0; r < 4; r++) acc[a][b][r] = 0.f;

  const int srow = tid >> 3, sch = tid & 7;
  for (int k0 = 0; k0 < Kpad; k0 += 64) {
#pragma unroll
    for (int p = 0; p < 4; p++) {
      int row = srow + p * 32;
      *(uint4*)&As[row][sch * 8] = *(const uint4*)(A + (Arow0 + row) * lda + k0 + sch * 8);
      *(uint4*)&Bs[row][sch * 8] = *(const uint4*)(Bt + (Brow0 + row) * ldb + k0 + sch * 8);
    }
    __syncthreads();
#pragma unroll
    for (int s = 0; s < 2; s++) {
      bfrag a[4], b[4];
#pragma unroll
      for (int mt = 0; mt < 4; mt++) a[mt] = *(const bfrag*)&As[rbase + mt*16 + fr][s*32 + fq*8];
#pragma unroll
      for (int nt = 0; nt < 4; nt++) b[nt] = *(const bfrag*)&Bs[cbase + nt*16 + fr][s*32 + fq*8];
#pragma unroll
      for (int mt = 0; mt < 4; mt++)
#pragma unroll
        for (int nt = 0; nt < 4; nt++)
          acc[mt][nt] = __builtin_amdgcn_mfma_f32_16x16x32_bf16(a[mt], b[nt], acc[mt][nt], 0, 0, 0);
    }
    __syncthreads();
  }
#pragma unroll
  for (int mt = 0; mt < 4; mt++) {
#pragma unroll
    for (int nt = 0; nt < 4; nt++) {
      int gc = (int)Brow0 + cbase + nt * 16 + fr;
      float bias_v = (bias != nullptr && gc < N) ? bias[gc] : 0.f;
#pragma unroll
      for (int r = 0; r < 4; r++) {
        int gr = (int)Arow0 + rbase + mt * 16 + fq * 4 + r;
        if (gr < M && gc < Nz) {
          float v = 0.f;
          if (gc < N) {
            v = acc[mt][nt][r] + bias_v;
            if (RELU) v = fmaxf(v, 0.f);
          }
          if (OBF) ((unsigned short*)Cv)[(size_t)gr * ldc + gc] = f2b(v);
          else     ((float*)Cv)[(size_t)gr * ldc + gc] = v;
        }
      }
    }
  }
}

// ---------------- message phase ----------------
// raw[r<640][704] bf16 ; memb[r][192] bf16 (memory[a] padded)
__global__ __launch_bounds__(256) void build_raw(
    const float* memory, const float* edge_features, const float* last_update,
    const float* time_w, const float* time_b,
    const float* num_w1, const float* num_b1, const float* num_w2, const float* num_b2,
    const float* edge_times, const float* num_conn,
    const int* src, const int* dst, const int* edge_idxs,
    unsigned short* raw, unsigned short* memb) {
  const int r = blockIdx.x, t = threadIdx.x;
  const int e = (r < BB) ? r : r - BB;
  const int a = (r < BB) ? src[e] : dst[e];
  const int b = (r < BB) ? dst[e] : src[e];
  const int ei = edge_idxs[e];
  const float dt = edge_times[e] - last_update[a];
  for (int c = t; c < 704; c += 256) {
    float v;
    if (c < 172) v = memory[(size_t)a*DD + c];
    else if (c < 344) v = memory[(size_t)b*DD + (c-172)];
    else if (c < 516) v = edge_features[(size_t)ei*DD + (c-344)];
    else if (c < 688) { int d = c-516; v = cosf(dt * time_w[d] + time_b[d]); }
    else if (c == 688) v = fmaxf(num_conn[e]*num_w1[0]+num_b1[0], 0.f)*num_w2[0]+num_b2[0];
    else v = 0.f;
    raw[(size_t)r*704 + c] = f2b(v);
  }
  for (int d = t; d < 192; d += 256)
    memb[(size_t)r*192 + d] = (d < 172) ? f2b(memory[(size_t)a*DD + d]) : 0;
}

__global__ __launch_bounds__(192) void gru_gate(
    const float* gi, const float* gh, const float* memory,
    const int* src, const int* dst, float* upd) {
  int r = blockIdx.x, t = threadIdx.x;
  int a = (r < BB) ? src[r] : dst[r - BB];
  if (t < DD) {
    float i_r = gi[(size_t)r*516 + t], i_z = gi[(size_t)r*516 + DD + t], i_n = gi[(size_t)r*516 + 2*DD + t];
    float h_r = gh[(size_t)r*516 + t], h_z = gh[(size_t)r*516 + DD + t], h_n = gh[(size_t)r*516 + 2*DD + t];
    float rr = sigm(i_r + h_r);
    float z  = sigm(i_z + h_z);
    float nn = tanhf(i_n + rr * h_n);
    float h  = memory[(size_t)a*DD + t];
    upd[(size_t)r*DD + t] = (1.f - z) * nn + z * h;
  }
}

// ---------------- q_in builders ----------------
__global__ __launch_bounds__(256) void build_qin0(
    const int* src, const int* dst, const int* neg, const int* n1_nb,
    const float* memory, const float* upd, const int* map, const float* nf,
    const float* time_b, unsigned short* qin) {
  int i = blockIdx.x, t = threadIdx.x;
  int node = (i < BB) ? src[i] : (i < 2*BB) ? dst[i-BB] : (i < 3*BB) ? neg[i-2*BB] : n1_nb[i-3*BB];
  int m = map[node];
  const float* mrow = (m >= 0) ? upd + (size_t)m*DD : memory + (size_t)node*DD;
  for (int c = t; c < QIN_K; c += 256) {
    unsigned short v;
    if (c < DD) v = f2b(mrow[c] + nf[(size_t)node*DD + c]);
    else if (c < 2*DD) v = f2b(cosf(time_b[c - DD]));
    else v = 0;
    qin[(size_t)i*QIN_K + c] = v;
  }
}

__global__ __launch_bounds__(256) void build_qin1(
    const unsigned short* conv0, const float* time_b, unsigned short* qin1) {
  int i = blockIdx.x, t = threadIdx.x;
  for (int c = t; c < QIN_K; c += 256) {
    unsigned short v;
    if (c < DD) v = conv0[(size_t)i*DD + c];
    else if (c < 2*DD) v = f2b(cosf(time_b[c - DD]));
    else v = 0;
    qin1[(size_t)i*QIN_K + c] = v;
  }
}

// ---------------- fused per-node attention core ----------------
// Builds k_in in LDS, scores via qk-fold, softmax, emits c vector [1088] bf16.
template <int MODE>  // 0: layer-0 (memory/nf gathers, n1/n2 split), 1: layer-1 (conv0, n1)
__global__ __launch_bounds__(256) void attn_core(
    const unsigned short* __restrict__ qk,   // [n][QKLD]
    const int* n1_nb, const int* n1_ei, const float* n1_et,
    const int* n2_nb, const int* n2_ei, const float* n2_et,
    const float* edge_times,
    const float* memory, const float* upd, const int* map, const float* nf,
    const unsigned short* conv0,
    const float* ef, const float* time_w, const float* time_b,
    unsigned short* __restrict__ C) {
  __shared__ unsigned short s_kin[KK][520];
  __shared__ float s_qk[1032];
  __shared__ float s_part[20][8];
  __shared__ float s_att[2][KK];
  __shared__ float s_qbk[2];
  __shared__ int s_nb[KK]; __shared__ int s_ei[KK]; __shared__ float s_et[KK];
  const int i = blockIdx.x, t = threadIdx.x;
  float ts;
  if (MODE == 0) {
    if (i < 3*BB) {
      if (t < KK) { s_nb[t] = n1_nb[(size_t)i*KK+t]; s_ei[t] = n1_ei[(size_t)i*KK+t]; s_et[t] = n1_et[(size_t)i*KK+t]; }
      ts = edge_times[i % BB];
    } else {
      int j = i - 3*BB;
      if (t < KK) { s_nb[t] = n2_nb[(size_t)j*KK+t]; s_ei[t] = n2_ei[(size_t)j*KK+t]; s_et[t] = n2_et[(size_t)j*KK+t]; }
      ts = edge_times[(j / KK) % BB];
    }
  } else {
    if (t < KK) { s_nb[t] = n1_nb[(size_t)i*KK+t]; s_ei[t] = n1_ei[(size_t)i*KK+t]; s_et[t] = n1_et[(size_t)i*KK+t]; }
    ts = edge_times[i % BB];
  }
  for (int c = t; c < 1032; c += 256) s_qk[c] = b2f(qk[(size_t)i*QKLD + c]);
  if (t < 2) s_qbk[t] = b2f(qk[(size_t)i*QKLD + 1032 + t]);
  __syncthreads();

  // build k_in rows (bf16) in LDS
  for (int f = t; f < KK*520; f += 256) {
    int k = f / 520, c = f - k * 520;
    unsigned short v;
    if (c < DD) {
      if (MODE == 0) {
        int nb = s_nb[k]; int m = map[nb];
        float x = ((m >= 0) ? upd[(size_t)m*DD + c] : memory[(size_t)nb*DD + c]) + nf[(size_t)nb*DD + c];
        v = f2b(x);
      } else {
        v = conv0[(size_t)(3*BB + i*KK + k)*DD + c];
      }
    } else if (c < 2*DD) {
      v = f2b(ef[(size_t)s_ei[k]*DD + (c - DD)]);
    } else if (c < 3*DD) {
      int d = c - 2*DD;
      v = f2b(cosf((ts - s_et[k]) * time_w[d] + time_b[d]));
    } else v = 0;
    s_kin[k][c] = v;
  }
  __syncthreads();

  // scores: 20 (h,kk) pairs x 8 sub-lanes over 516
  if (t < 160) {
    int p = t >> 3, sub = t & 7;
    int h = p / KK, kk = p - h * KK;
    float acc = 0.f;
    for (int x = sub; x < 516; x += 8) acc += s_qk[h*516 + x] * b2f(s_kin[kk][x]);
    s_part[p][sub] = acc;
  }
  __syncthreads();
  if (t < 20) {
    float sc = 0.f;
    for (int s = 0; s < 8; s++) sc += s_part[t][s];
    int h = t / KK, kk = t - h * KK;
    sc = (sc + s_qbk[h]) * 0.07624928516630234f;  // 1/sqrt(172)
    if (s_nb[kk] == 0) sc = -1e9f;
    s_part[t][0] = sc;
  }
  __syncthreads();
  if (t < 2) {
    float mx = -1e30f;
    for (int kk = 0; kk < KK; kk++) mx = fmaxf(mx, s_part[t*KK + kk][0]);
    float e[KK], sum = 0.f;
    for (int kk = 0; kk < KK; kk++) { e[kk] = expf(s_part[t*KK + kk][0] - mx); sum += e[kk]; }
    float inv = 1.f / sum;
    for (int kk = 0; kk < KK; kk++) s_att[t][kk] = e[kk] * inv;
  }
  __syncthreads();

  // c vector: c_h[x] = sum_k attn_h[k] * k_in[k][x]
  for (int j = t; j < CK; j += 256) {
    float acc = 0.f;
    if (j < 1032) {
      int h = j / 516, x = j - h * 516;
#pragma unroll
      for (int kk = 0; kk < KK; kk++) acc += s_att[h][kk] * b2f(s_kin[kk][x]);
    }
    C[(size_t)i*CK + j] = f2b(acc);
  }
}

// mrgA row = [allmask? 0 : o2 (344) | src_feat (172) | 0], bf16 stride 576
__global__ __launch_bounds__(256) void build_mrgA(
    const unsigned short* o2 /*ld 384*/, const int* nbA, const int* nbB, int split,
    const unsigned short* srcf, int ld_src, unsigned short* mrgA) {
  int i = blockIdx.x, t = threadIdx.x;
  const int* nbp = (i < split) ? nbA + (size_t)i*KK : nbB + (size_t)(i - split)*KK;
  __shared__ int allm;
  if (t == 0) {
    int a = 1;
    for (int k = 0; k < KK; k++) if (nbp[k] != 0) a = 0;
    allm = a;
  }
  __syncthreads();
  for (int c = t; c < KIN_K; c += 256) {
    unsigned short v;
    if (c < 2*DD) v = allm ? (unsigned short)0 : o2[(size_t)i*QIN_K + c];
    else if (c < 3*DD) v = srcf[(size_t)i*ld_src + (c - 2*DD)];
    else v = 0;
    mrgA[(size_t)i*KIN_K + c] = v;
  }
}

// ---------------- launch ----------------
extern "C" void kernel_launch(void* const* d_in, const int* in_sizes, int n_in,
                              void* d_out, int out_size, void* d_ws, size_t ws_size,
                              hipStream_t stream) {
  const float* node_features = (const float*)d_in[0];
  const float* edge_features = (const float*)d_in[1];
  const float* memory        = (const float*)d_in[2];
  const float* last_update   = (const float*)d_in[3];
  const float* time_w        = (const float*)d_in[4];
  const float* time_b        = (const float*)d_in[5];
  const float* num_w1 = (const float*)d_in[6];
  const float* num_b1 = (const float*)d_in[7];
  const float* num_w2 = (const float*)d_in[8];
  const float* num_b2 = (const float*)d_in[9];
  const float* msg_w1 = (const float*)d_in[10];
  const float* msg_b1 = (const float*)d_in[11];
  const float* msg_w2 = (const float*)d_in[12];
  const float* msg_b2 = (const float*)d_in[13];
  const float* gru_wih = (const float*)d_in[14];
  const float* gru_whh = (const float*)d_in[15];
  const float* gru_bih = (const float*)d_in[16];
  const float* gru_bhh = (const float*)d_in[17];
  const float* att_wq = (const float*)d_in[18];
  const float* att_wk = (const float*)d_in[19];
  const float* att_wv = (const float*)d_in[20];
  const float* att_bq = (const float*)d_in[21];
  const float* att_bk = (const float*)d_in[22];
  const float* att_bv = (const float*)d_in[23];
  const float* att_wo = (const float*)d_in[24];
  const float* att_bo = (const float*)d_in[25];
  const float* mrg_w1 = (const float*)d_in[26];
  const float* mrg_b1 = (const float*)d_in[27];
  const float* mrg_w2 = (const float*)d_in[28];
  const float* mrg_b2 = (const float*)d_in[29];
  const float* edge_times = (const float*)d_in[30];
  const float* num_conn   = (const float*)d_in[31];
  const float* n1_et = (const float*)d_in[32];
  const float* n2_et = (const float*)d_in[33];
  const int* src = (const int*)d_in[34];
  const int* dst = (const int*)d_in[35];
  const int* neg = (const int*)d_in[36];
  const int* edge_idxs = (const int*)d_in[37];
  const int* n1_nb   = (const int*)d_in[38];
  const int* n1_eidx = (const int*)d_in[39];
  const int* n2_nb   = (const int*)d_in[40];
  const int* n2_eidx = (const int*)d_in[41];

  // ---- workspace (persistent ~42.5MB + transient region ~23MB) ----
  char* ws = (char*)d_ws;
  size_t off = 0;
  auto alloc = [&](size_t b) -> char* {
    char* p = ws + off; off = (off + b + 255) & ~(size_t)255; return p;
  };
  int* map  = (int*)alloc((size_t)NN * 4);
  float* upd = (float*)alloc((size_t)2*BB*DD * 4);
  unsigned short* wqh_b = (unsigned short*)alloc((size_t)SZ_WQH * 2);
  unsigned short* wkh_b = (unsigned short*)alloc((size_t)SZ_WKH * 2);
  unsigned short* wvh_b = (unsigned short*)alloc((size_t)SZ_WVH * 2);
  unsigned short* woT_b = (unsigned short*)alloc((size_t)SZ_WOT * 2);
  unsigned short* wm1_t = (unsigned short*)alloc((size_t)SZ_M1 * 2);
  unsigned short* wm2_t = (unsigned short*)alloc((size_t)SZ_M2 * 2);
  unsigned short* msgw1t = (unsigned short*)alloc((size_t)SZ_MW1 * 2);
  unsigned short* msgw2t = (unsigned short*)alloc((size_t)SZ_MW2 * 2);
  unsigned short* gruwih_b = (unsigned short*)alloc((size_t)SZ_GIH * 2);
  unsigned short* gruwhh_b = (unsigned short*)alloc((size_t)SZ_GHH * 2);
  unsigned short* Gcat = (unsigned short*)alloc((size_t)2*GROWS*384 * 2);
  unsigned short* Mcat = (unsigned short*)alloc((size_t)2*384*CK * 2);
  float* bqk  = (float*)alloc((size_t)2*QKLD * 4);
  float* bvwo = (float*)alloc((size_t)2*344 * 4);
  unsigned short* qin0 = (unsigned short*)alloc((size_t)R0P*QIN_K * 2);
  unsigned short* Cbuf = (unsigned short*)alloc((size_t)R0P*CK * 2);   // C0, later C1
  unsigned short* conv0 = (unsigned short*)alloc((size_t)R0P*DD * 2);

  char* T = ws + off;  // transient region, phases stream-serialized
  // msg phase overlay
  size_t mo = 0;
  auto ma = [&](size_t b) -> char* { char* p = T + mo; mo = (mo + b + 255) & ~(size_t)255; return p; };
  unsigned short* raw  = (unsigned short*)ma((size_t)640*704 * 2);
  unsigned short* memb = (unsigned short*)ma((size_t)640*192 * 2);
  unsigned short* h1m  = (unsigned short*)ma((size_t)640*384 * 2);
  unsigned short* msgb = (unsigned short*)ma((size_t)640*128 * 2);
  float* gi = (float*)ma((size_t)600*516 * 4);
  float* gh = (float*)ma((size_t)600*516 * 4);
  // qk0 overlay (after gru_gate)
  unsigned short* qk0 = (unsigned short*)T;                            // R0P*QKLD*2 = 20.8MB
  // o2/merge overlay (after attn_core<0>)
  size_t oo = 0;
  auto oa = [&](size_t b) -> char* { char* p = T + oo; oo = (oo + b + 255) & ~(size_t)255; return p; };
  unsigned short* o2_0  = (unsigned short*)oa((size_t)R0P*QIN_K * 2);
  unsigned short* mrgA0 = (unsigned short*)oa((size_t)R0P*KIN_K * 2);
  unsigned short* h0    = (unsigned short*)oa((size_t)R0P*H_K * 2);
  // layer-1 overlay (after conv0 written)
  size_t lo = 0;
  auto la = [&](size_t b) -> char* { char* p = T + lo; lo = (lo + b + 255) & ~(size_t)255; return p; };
  unsigned short* qin1  = (unsigned short*)la((size_t)L1P*QIN_K * 2);
  unsigned short* qk1   = (unsigned short*)la((size_t)L1P*QKLD * 2);
  unsigned short* o2_1  = (unsigned short*)la((size_t)L1P*QIN_K * 2);
  unsigned short* mrgA1 = (unsigned short*)la((size_t)L1P*KIN_K * 2);
  unsigned short* h1b   = (unsigned short*)la((size_t)L1P*H_K * 2);

  // ---- phase A: map + weight preps ----
  fill_map<<<(NN + 255)/256, 256, 0, stream>>>(map);
  set_map<<<(BB + 63)/64, 64, 0, stream>>>(map, src, dst);
  {
    long tot = (long)SZ_WQH + SZ_WKH + SZ_WVH + SZ_WOT + SZ_M1 + SZ_M2 + SZ_MW1 + SZ_MW2 + SZ_GIH + SZ_GHH;
    prep_w<<<(int)((tot + 255)/256), 256, 0, stream>>>(
        att_wq, att_wk, att_wv, att_wo, mrg_w1, mrg_w2, msg_w1, msg_w2, gru_wih, gru_whh,
        wqh_b, wkh_b, wvh_b, woT_b, wm1_t, wm2_t, msgw1t, msgw2t, gruwih_b, gruwhh_b);
    long tb = (long)SB_QK + SB_VO + SB_GV;
    prep_bias<<<(int)((tb + 255)/256), 256, 0, stream>>>(
        att_wq, att_wk, att_wo, att_bq, att_bk, att_bv, att_bo, bqk, bvwo, Gcat);
  }
  // G gemms: Gcat rows [h*516 + x][y] = sum_d Wk[x][hd] Wq[y][hd]
  for (int l = 0; l < 2; l++)
    for (int h = 0; h < 2; h++)
      gemm128<true, false><<<dim3(5, 3), 256, 0, stream>>>(
          wkh_b + (size_t)(l*2+h)*640*192, 192,
          wqh_b + (size_t)(l*2+h)*384*192, 192, nullptr,
          Gcat + (size_t)l*GROWS*384 + (size_t)h*516*384, 384, 516, 344, 384, 192);
  // Mcat gemms: Mcat[j][h*516+x] = sum_d Wo[hd][j] Wv[x][hd]
  for (int l = 0; l < 2; l++)
    for (int h = 0; h < 2; h++)
      gemm128<true, false><<<dim3(3, 5), 256, 0, stream>>>(
          woT_b + (size_t)(l*2+h)*384*192, 192,
          wvh_b + (size_t)(l*2+h)*640*192, 192, nullptr,
          Mcat + (size_t)l*384*CK + (size_t)h*516, CK, 344, 516, (h == 0 ? 516 : 572), 192);

  // ---- phase B: message + GRU memory update (GEMM-ified) ----
  build_raw<<<2*BB, 256, 0, stream>>>(
      memory, edge_features, last_update, time_w, time_b,
      num_w1, num_b1, num_w2, num_b2, edge_times, num_conn,
      src, dst, edge_idxs, raw, memb);
  gemm128<true, true><<<dim3(5, 3), 256, 0, stream>>>(
      raw, 704, msgw1t, 704, msg_b1, h1m, 384, 600, 344, 384, 704);
  gemm128<true, false><<<dim3(5, 1), 256, 0, stream>>>(
      h1m, 384, msgw2t, 384, msg_b2, msgb, 128, 600, 100, 128, 384);
  gemm128<false, false><<<dim3(5, 5), 256, 0, stream>>>(
      msgb, 128, gruwih_b, 128, gru_bih, gi, 516, 600, 516, 516, 128);
  gemm128<false, false><<<dim3(5, 5), 256, 0, stream>>>(
      memb, 192, gruwhh_b, 192, gru_bhh, gh, 516, 600, 516, 516, 192);
  gru_gate<<<2*BB, 192, 0, stream>>>(gi, gh, memory, src, dst, upd);

  // ---- layer-0 ----
  build_qin0<<<R0T, 256, 0, stream>>>(src, dst, neg, n1_nb, memory, upd, map,
                                      node_features, time_b, qin0);
  gemm128<true, false><<<dim3(R0P/128, 9), 256, 0, stream>>>(
      qin0, QIN_K, Gcat, 384, bqk, qk0, QKLD, R0T, QKN, QKN, QIN_K);
  attn_core<0><<<R0T, 256, 0, stream>>>(
      qk0, n1_nb, n1_eidx, n1_et, n2_nb, n2_eidx, n2_et, edge_times,
      memory, upd, map, node_features, conv0,
      edge_features, time_w, time_b, Cbuf);
  gemm128<true, false><<<dim3(R0P/128, 3), 256, 0, stream>>>(
      Cbuf, CK, Mcat, CK, bvwo, o2_0, QIN_K, R0T, 344, 344, CK);
  build_mrgA<<<R0T, 256, 0, stream>>>(o2_0, n1_nb, n2_nb, 3*BB, qin0, QIN_K, mrgA0);
  gemm128<true, true><<<dim3(R0P/128, 2), 256, 0, stream>>>(
      mrgA0, KIN_K, wm1_t, KIN_K, mrg_b1, h0, H_K, R0T, 172, 192, KIN_K);
  gemm128<true, false><<<dim3(R0P/128, 2), 256, 0, stream>>>(
      h0, H_K, wm2_t, H_K, mrg_b2, conv0, DD, R0T, 172, 172, H_K);

  // ---- layer-1 ----
  build_qin1<<<3*BB, 256, 0, stream>>>(conv0, time_b, qin1);
  gemm128<true, false><<<dim3(L1P/128, 9), 256, 0, stream>>>(
      qin1, QIN_K, Gcat + (size_t)GROWS*384, 384, bqk + QKLD, qk1, QKLD, 3*BB, QKN, QKN, QIN_K);
  attn_core<1><<<3*BB, 256, 0, stream>>>(
      qk1, n1_nb, n1_eidx, n1_et, n1_nb, n1_eidx, n1_et, edge_times,
      memory, upd, map, node_features, conv0,
      edge_features, time_w, time_b, Cbuf);
  gemm128<true, false><<<dim3(L1P/128, 3), 256, 0, stream>>>(
      Cbuf, CK, Mcat + (size_t)384*CK, CK, bvwo + 344, o2_1, QIN_K, 3*BB, 344, 344, CK);
  build_mrgA<<<3*BB, 256, 0, stream>>>(o2_1, n1_nb, n1_nb, 3*BB, conv0, DD, mrgA1);
  gemm128<true, true><<<dim3(L1P/128, 2), 256, 0, stream>>>(
      mrgA1, KIN_K, wm1_t + (size_t)256*KIN_K, KIN_K, mrg_b1 + 172, h1b, H_K, 3*BB, 172, 192, KIN_K);
  gemm128<false, false><<<dim3(L1P/128, 2), 256, 0, stream>>>(
      h1b, H_K, wm2_t + (size_t)256*H_K, H_K, mrg_b2 + 172, (float*)d_out, DD, 3*BB, 172, 172, H_K);
}